// Round 1
// baseline (2822.138 us; speedup 1.0000x reference)
//
#include <hip/hip_runtime.h>
#include <math.h>

#define DIMD   512
#define EMBED  768
#define MEDIM  64
#define BATCH  8192
#define NSTEP  10

// ---------------------------------------------------------------------------
// Generic f32 GEMM:  C[M,N] = act( A[M,K] * Bt[N,K]^T + bias[N] (+ add[M,N]) )
// Bt is row-major [N,K] (i.e. computes A @ W^T for torch-style weights).
// ACT: 0=none, 1=relu, 2=tanh.  MASK: per-row 0/1 multiply on A (flags).
// Tiles: 64x64, BK=16, 256 threads, 4x4 micro-tile per thread.
// All M,N,K in this problem are multiples of 64/64/16 -> no bounds checks.
// ---------------------------------------------------------------------------
template<int ACT, bool MASK, bool ADD>
__global__ __launch_bounds__(256)
void gemm_bt(const float* __restrict__ A, const float* __restrict__ Bt,
             const float* __restrict__ bias, const float* __restrict__ add,
             const int* __restrict__ rowflag, float* __restrict__ C,
             int M, int N, int K)
{
    __shared__ float As[16][68];   // [k][row], pad to 68 for bank spread + 16B align
    __shared__ float Bs[16][68];   // [k][col]
    __shared__ float msk[64];

    const int tid  = threadIdx.x;
    const int row0 = blockIdx.y * 64;
    const int col0 = blockIdx.x * 64;

    if (MASK) {
        if (tid < 64)
            msk[tid] = rowflag ? (rowflag[row0 + tid] ? 1.0f : 0.0f) : 1.0f;
        __syncthreads();
    }

    const int lr  = tid >> 2;   // 0..63 : row (A) / col (B) within tile
    const int lk4 = tid & 3;    // which float4 along k

    const float* Aptr = A + (size_t)(row0 + lr) * K + lk4 * 4;
    const float* Bptr = Bt + (size_t)(col0 + lr) * K + lk4 * 4;

    const int ty = tid >> 4;    // 0..15 row group
    const int tx = tid & 15;    // 0..15 col group

    float acc[4][4];
#pragma unroll
    for (int i = 0; i < 4; ++i)
#pragma unroll
        for (int j = 0; j < 4; ++j) acc[i][j] = 0.0f;

    float mrow = 1.0f;
    if (MASK) mrow = msk[lr];

    for (int k0 = 0; k0 < K; k0 += 16) {
        float4 av = *reinterpret_cast<const float4*>(Aptr + k0);
        float4 bv = *reinterpret_cast<const float4*>(Bptr + k0);
        if (MASK) { av.x *= mrow; av.y *= mrow; av.z *= mrow; av.w *= mrow; }
        As[lk4 * 4 + 0][lr] = av.x;
        As[lk4 * 4 + 1][lr] = av.y;
        As[lk4 * 4 + 2][lr] = av.z;
        As[lk4 * 4 + 3][lr] = av.w;
        Bs[lk4 * 4 + 0][lr] = bv.x;
        Bs[lk4 * 4 + 1][lr] = bv.y;
        Bs[lk4 * 4 + 2][lr] = bv.z;
        Bs[lk4 * 4 + 3][lr] = bv.w;
        __syncthreads();
#pragma unroll
        for (int kk = 0; kk < 16; ++kk) {
            const float4 a = *reinterpret_cast<const float4*>(&As[kk][ty * 4]);
            const float4 b = *reinterpret_cast<const float4*>(&Bs[kk][tx * 4]);
            acc[0][0] += a.x * b.x; acc[0][1] += a.x * b.y; acc[0][2] += a.x * b.z; acc[0][3] += a.x * b.w;
            acc[1][0] += a.y * b.x; acc[1][1] += a.y * b.y; acc[1][2] += a.y * b.z; acc[1][3] += a.y * b.w;
            acc[2][0] += a.z * b.x; acc[2][1] += a.z * b.y; acc[2][2] += a.z * b.z; acc[2][3] += a.z * b.w;
            acc[3][0] += a.w * b.x; acc[3][1] += a.w * b.y; acc[3][2] += a.w * b.z; acc[3][3] += a.w * b.w;
        }
        __syncthreads();
    }

#pragma unroll
    for (int i = 0; i < 4; ++i) {
        const int r = row0 + ty * 4 + i;
#pragma unroll
        for (int j = 0; j < 4; ++j) {
            const int c = col0 + tx * 4 + j;
            float v = acc[i][j] + bias[c];
            if (ADD) v += add[(size_t)r * N + c];
            if (ACT == 1) v = fmaxf(v, 0.0f);
            if (ACT == 2) v = tanhf(v);
            C[(size_t)r * N + c] = v;
        }
    }
}

// h0[b,:] = start[:]  (broadcast)
__global__ __launch_bounds__(256)
void bcast_start(const float* __restrict__ start, float* __restrict__ h)
{
    const int n4 = BATCH * DIMD / 4;
    const float4* s4 = reinterpret_cast<const float4*>(start);
    float4* h4 = reinterpret_cast<float4*>(h);
    for (int idx = blockIdx.x * blockDim.x + threadIdx.x; idx < n4;
         idx += gridDim.x * blockDim.x) {
        h4[idx] = s4[idx & (DIMD / 4 - 1)];
    }
}

// xcat[b, 0:512] = h[b,:] ; xcat[b, 512:576] = move_emb[moves[b], :]
__global__ __launch_bounds__(256)
void build_xcat(const float* __restrict__ h, const float* __restrict__ move_emb,
                const int* __restrict__ moves, float* __restrict__ xcat)
{
    const int C4 = (DIMD + MEDIM) / 4;   // 144
    const int n4 = BATCH * C4;
    for (int idx = blockIdx.x * blockDim.x + threadIdx.x; idx < n4;
         idx += gridDim.x * blockDim.x) {
        const int b  = idx / C4;
        const int c4 = idx - b * C4;
        float4 v;
        if (c4 < DIMD / 4) {
            v = reinterpret_cast<const float4*>(h + (size_t)b * DIMD)[c4];
        } else {
            v = reinterpret_cast<const float4*>(move_emb +
                  (size_t)moves[b] * MEDIM)[c4 - DIMD / 4];
        }
        reinterpret_cast<float4*>(xcat + (size_t)b * (DIMD + MEDIM))[c4] = v;
    }
}

// out[b] = dot(x[b,:512], out_w[:512]) + out_b   (one wave per row)
__global__ __launch_bounds__(256)
void out_head(const float* __restrict__ x, const float* __restrict__ out_w,
              const float* __restrict__ out_b, float* __restrict__ out)
{
    const int wid  = threadIdx.x >> 6;
    const int lane = threadIdx.x & 63;
    const int row  = blockIdx.x * 4 + wid;
    const float4* xr = reinterpret_cast<const float4*>(x + (size_t)row * DIMD);
    const float4* wr = reinterpret_cast<const float4*>(out_w);
    float s = 0.0f;
#pragma unroll
    for (int t = 0; t < 2; ++t) {
        const float4 xv = xr[lane * 2 + t];
        const float4 wv = wr[lane * 2 + t];
        s += xv.x * wv.x + xv.y * wv.y + xv.z * wv.z + xv.w * wv.w;
    }
#pragma unroll
    for (int off = 32; off; off >>= 1) s += __shfl_down(s, off, 64);
    if (lane == 0) out[row] = s + out_b[0];
}

extern "C" void kernel_launch(void* const* d_in, const int* in_sizes, int n_in,
                              void* d_out, int out_size, void* d_ws, size_t ws_size,
                              hipStream_t stream)
{
    const float* boards  = (const float*)d_in[0];
    const int*   flags   = (const int*)  d_in[1];
    /* themes d_in[2] unused by reference */
    const int*   moves   = (const int*)  d_in[3];
    const float* start   = (const float*)d_in[4];
    const float* red_w   = (const float*)d_in[5];
    const float* red_b   = (const float*)d_in[6];
    const float* ca_w    = (const float*)d_in[7];
    const float* ca_b    = (const float*)d_in[8];
    const float* cb_w    = (const float*)d_in[9];
    const float* cb_b    = (const float*)d_in[10];
    const float* move_emb= (const float*)d_in[11];
    const float* fc1_w   = (const float*)d_in[12];
    const float* fc1_b   = (const float*)d_in[13];
    const float* fc2_w   = (const float*)d_in[14];
    const float* fc2_b   = (const float*)d_in[15];
    const float* fc3_w   = (const float*)d_in[16];
    const float* fc3_b   = (const float*)d_in[17];
    const float* fc4_w   = (const float*)d_in[18];
    const float* fc4_b   = (const float*)d_in[19];
    const float* fc5_w   = (const float*)d_in[20];
    const float* fc5_b   = (const float*)d_in[21];
    const float* out_w   = (const float*)d_in[22];
    const float* out_b   = (const float*)d_in[23];

    float* ws = (float*)d_ws;
    const size_t M4 = (size_t)4 << 20;        // 4M floats = one [8192,512] buffer
    float* e    = ws;                          // [8192,512]
    float* eb   = ws + 1 * M4;                 // [8192,512]
    float* hA   = ws + 2 * M4;                 // [8192,512]
    float* hB   = ws + 3 * M4;                 // [8192,512]
    float* xcat = ws + 4 * M4;                 // [8192,576] (4.5M floats)
    float* x1   = ws;                          // reuse e    (dead after scan)
    float* x2   = ws + 1 * M4;                 // reuse eb
    float* x3   = ws + 2 * M4;                 // [8192,1024] over hA+hB (dead)
    float* x4   = ws + 4 * M4;                 // [8192,1024] over xcat (dead)
    float* x5   = ws;                          // reuse x1 region (dead after fc2)

    const dim3 blk(256);
    const dim3 g512(DIMD / 64, BATCH / 64);    // (8,128)
    const dim3 g1024(1024 / 64, BATCH / 64);   // (16,128)

    // h0 = broadcast(start)
    bcast_start<<<1024, blk, 0, stream>>>(start, hA);

    float* hcur = hA;
    float* hnxt = hB;
    for (int s = 0; s < NSTEP; ++s) {
        const float* bstep = boards + (size_t)s * BATCH * EMBED;
        const int* fstep = (s < 2) ? nullptr : (flags + (size_t)(s - 2) * BATCH);
        // e = relu(mask(boards_s) @ red_w^T + red_b)
        gemm_bt<1, true, false><<<g512, blk, 0, stream>>>(
            bstep, red_w, red_b, nullptr, fstep, e, BATCH, DIMD, EMBED);
        // eb = e @ cb_w^T + cb_b
        gemm_bt<0, false, false><<<g512, blk, 0, stream>>>(
            e, cb_w, cb_b, nullptr, nullptr, eb, BATCH, DIMD, DIMD);
        // h = tanh(h @ ca_w^T + ca_b + eb)
        gemm_bt<2, false, true><<<g512, blk, 0, stream>>>(
            hcur, ca_w, ca_b, eb, nullptr, hnxt, BATCH, DIMD, DIMD);
        float* t = hcur; hcur = hnxt; hnxt = t;
    }

    // xcat = [h, move_emb[moves]]
    build_xcat<<<1024, blk, 0, stream>>>(hcur, move_emb, moves, xcat);

    // MLP head
    gemm_bt<1, false, false><<<g512, blk, 0, stream>>>(
        xcat, fc1_w, fc1_b, nullptr, nullptr, x1, BATCH, DIMD, DIMD + MEDIM);
    gemm_bt<1, false, false><<<g512, blk, 0, stream>>>(
        x1, fc2_w, fc2_b, nullptr, nullptr, x2, BATCH, DIMD, DIMD);
    gemm_bt<1, false, false><<<g1024, blk, 0, stream>>>(
        x2, fc3_w, fc3_b, nullptr, nullptr, x3, BATCH, 1024, DIMD);
    gemm_bt<1, false, false><<<g1024, blk, 0, stream>>>(
        x3, fc4_w, fc4_b, nullptr, nullptr, x4, BATCH, 1024, 1024);
    gemm_bt<1, false, false><<<g512, blk, 0, stream>>>(
        x4, fc5_w, fc5_b, nullptr, nullptr, x5, BATCH, DIMD, 1024);

    out_head<<<BATCH / 4, blk, 0, stream>>>(x5, out_w, out_b, (float*)d_out);
}

// Round 2
// 670.650 us; speedup vs baseline: 4.2081x; 4.2081x over previous
//
#include <hip/hip_runtime.h>
#include <math.h>

#define BATCH  8192
#define EMBED  768
#define DIMD   512
#define MEDIM  64
#define NSTEP  10

typedef __bf16 bf16x8 __attribute__((ext_vector_type(8)));
typedef float  f32x4  __attribute__((ext_vector_type(4)));

// ---- async global->LDS, 16B per lane (dest = wave-uniform base + lane*16) ----
__device__ __forceinline__ void load16_lds(const __bf16* g, __bf16* l)
{
    auto* gp = (__attribute__((address_space(1))) char*)(uintptr_t)(const void*)g;
    auto* lp = (__attribute__((address_space(3))) char*)(unsigned int)(uintptr_t)(void*)l;
    __builtin_amdgcn_global_load_lds(gp, lp, 16, 0, 0);
}

// ---------------------------------------------------------------------------
// bf16 MFMA GEMM: C[M,N] = act(A[M,K] @ Bt[N,K]^T + bias[N] (+ add)) -> bf16
// BM=64, BN=128, BK=32. 256 threads = 4 waves (2x2), 32x64 per wave.
// ACT: 0=none, 1=relu, 2=tanh. M%64==0, N%128==0, K%32==0.
// ---------------------------------------------------------------------------
#define BM 64
#define BN 128
#define BK 32

template<int ACT, bool ADD>
__global__ __launch_bounds__(256)
void gemm_bf16(const __bf16* __restrict__ A, const __bf16* __restrict__ Bt,
               const float* __restrict__ bias, const __bf16* __restrict__ add,
               __bf16* __restrict__ C, int M, int N, int K)
{
    __shared__ __bf16 lds[(BM + BN) * BK];   // 12 KB: A rows [0,64), B rows [64,192)

    const int tid  = threadIdx.x;
    const int wave = tid >> 6;
    const int lane = tid & 63;
    const int row0 = blockIdx.y * BM;
    const int col0 = blockIdx.x * BN;

    const int wr = (wave >> 1) * 32;   // wave row offset in tile
    const int wc = (wave & 1) * 64;    // wave col offset in tile

    const int fr = lane & 15;          // row/col within 16x16 fragment
    const int fk = (lane >> 4) * 8;    // k offset within 32

    f32x4 acc[2][4] = {};

    const int NCALL = (BM + BN) / 16;  // 12 x 1KB staging calls per K-step
    const int srow  = lane >> 2;       // 0..15 row within call
    const int skk   = (lane & 3) * 8;  // k offset of this lane's 16B

    for (int k0 = 0; k0 < K; k0 += BK) {
#pragma unroll
        for (int c = wave; c < NCALL; c += 4) {
            const int r = c * 16 + srow;             // 0..191
            const __bf16* g = (r < BM)
                ? (A  + (size_t)(row0 + r)        * K + k0 + skk)
                : (Bt + (size_t)(col0 + (r - BM)) * K + k0 + skk);
            load16_lds(g, &lds[c * 512]);
        }
        __syncthreads();   // compiler drains vmcnt(0) here -> LDS ready

        const __bf16* As = lds;
        const __bf16* Bs = lds + BM * BK;
        bf16x8 af[2], bfr[4];
#pragma unroll
        for (int m = 0; m < 2; ++m)
            af[m] = *(const bf16x8*)&As[(wr + m * 16 + fr) * BK + fk];
#pragma unroll
        for (int n = 0; n < 4; ++n)
            bfr[n] = *(const bf16x8*)&Bs[(wc + n * 16 + fr) * BK + fk];
#pragma unroll
        for (int m = 0; m < 2; ++m)
#pragma unroll
            for (int n = 0; n < 4; ++n)
                acc[m][n] = __builtin_amdgcn_mfma_f32_16x16x32_bf16(
                                af[m], bfr[n], acc[m][n], 0, 0, 0);
        __syncthreads();   // protect LDS before next stage
    }

    // epilogue: C/D layout col = lane&15, row = (lane>>4)*4 + reg  [m89-verified]
#pragma unroll
    for (int m = 0; m < 2; ++m) {
#pragma unroll
        for (int n = 0; n < 4; ++n) {
            const int cc = col0 + wc + n * 16 + (lane & 15);
            const float bb = bias[cc];
#pragma unroll
            for (int j = 0; j < 4; ++j) {
                const int rr = row0 + wr + m * 16 + (lane >> 4) * 4 + j;
                float v = acc[m][n][j] + bb;
                if (ADD) v += (float)add[(size_t)rr * N + cc];
                if (ACT == 1) v = fmaxf(v, 0.0f);
                if (ACT == 2) v = tanhf(v);
                C[(size_t)rr * N + cc] = (__bf16)v;
            }
        }
    }
}

// ---- boards[s] f32 -> bf16 with flag masking folded in (8 elems/thread) ----
__global__ __launch_bounds__(256)
void cvt_boards_step(const float* __restrict__ src, const int* __restrict__ flags,
                     __bf16* __restrict__ dst)
{
    const int idx = blockIdx.x * 256 + threadIdx.x;       // 786432 exact
    const int b = idx / 96;                                // 96 chunks per row of 768
    float m = 1.0f;
    if (flags) m = flags[b] ? 1.0f : 0.0f;
    const float4 v0 = ((const float4*)src)[idx * 2];
    const float4 v1 = ((const float4*)src)[idx * 2 + 1];
    bf16x8 o;
    o[0] = (__bf16)(v0.x * m); o[1] = (__bf16)(v0.y * m);
    o[2] = (__bf16)(v0.z * m); o[3] = (__bf16)(v0.w * m);
    o[4] = (__bf16)(v1.x * m); o[5] = (__bf16)(v1.y * m);
    o[6] = (__bf16)(v1.z * m); o[7] = (__bf16)(v1.w * m);
    *(bf16x8*)(dst + (size_t)idx * 8) = o;
}

// ---- all weights f32 -> one bf16 pool (hardcoded segment table) ----
enum : int { W_RED = 0, W_CA = 393216, W_CB = 655360, W_FC1 = 917504,
             W_FC2 = 1212416, W_FC3 = 1474560, W_FC4 = 1998848,
             W_FC5 = 3047424, W_ME = 3571712, W_TOTAL = 3575808 };

__global__ __launch_bounds__(256)
void cvt_weights(const float* __restrict__ w0, const float* __restrict__ w1,
                 const float* __restrict__ w2, const float* __restrict__ w3,
                 const float* __restrict__ w4, const float* __restrict__ w5,
                 const float* __restrict__ w6, const float* __restrict__ w7,
                 const float* __restrict__ w8, __bf16* __restrict__ dst)
{
    const int idx = blockIdx.x * 256 + threadIdx.x;       // 446976 exact
    if (idx >= W_TOTAL / 8) return;
    const int e = idx * 8;
    const float* src; int off;
    if      (e < W_CA)  { src = w0; off = W_RED; }
    else if (e < W_CB)  { src = w1; off = W_CA; }
    else if (e < W_FC1) { src = w2; off = W_CB; }
    else if (e < W_FC2) { src = w3; off = W_FC1; }
    else if (e < W_FC3) { src = w4; off = W_FC2; }
    else if (e < W_FC4) { src = w5; off = W_FC3; }
    else if (e < W_FC5) { src = w6; off = W_FC4; }
    else if (e < W_ME)  { src = w7; off = W_FC5; }
    else                { src = w8; off = W_ME; }
    const float4 v0 = ((const float4*)(src + (e - off)))[0];
    const float4 v1 = ((const float4*)(src + (e - off)))[1];
    bf16x8 o;
    o[0] = (__bf16)v0.x; o[1] = (__bf16)v0.y; o[2] = (__bf16)v0.z; o[3] = (__bf16)v0.w;
    o[4] = (__bf16)v1.x; o[5] = (__bf16)v1.y; o[6] = (__bf16)v1.z; o[7] = (__bf16)v1.w;
    *(bf16x8*)(dst + (size_t)e) = o;
}

// ---- h0[b,:] = bf16(start[:]) ----
__global__ __launch_bounds__(256)
void bcast_h0(const float* __restrict__ start, __bf16* __restrict__ h)
{
    const int idx = blockIdx.x * 256 + threadIdx.x;       // 524288 exact
    const int c8 = idx & 63;                               // 64 chunks per row of 512
    const float4 v0 = ((const float4*)start)[c8 * 2];
    const float4 v1 = ((const float4*)start)[c8 * 2 + 1];
    bf16x8 o;
    o[0] = (__bf16)v0.x; o[1] = (__bf16)v0.y; o[2] = (__bf16)v0.z; o[3] = (__bf16)v0.w;
    o[4] = (__bf16)v1.x; o[5] = (__bf16)v1.y; o[6] = (__bf16)v1.z; o[7] = (__bf16)v1.w;
    *(bf16x8*)(h + (size_t)idx * 8) = o;
}

// ---- xcat[b] = [h[b], move_emb_bf16[moves[b]]] ----
__global__ __launch_bounds__(256)
void build_xcat(const __bf16* __restrict__ h, const __bf16* __restrict__ me,
                const int* __restrict__ moves, __bf16* __restrict__ xcat)
{
    const int idx = blockIdx.x * 256 + threadIdx.x;       // 589824 exact
    const int b  = idx / 72;                               // 72 chunks per row of 576
    const int c8 = idx - b * 72;
    bf16x8 v;
    if (c8 < 64) v = ((const bf16x8*)(h + (size_t)b * DIMD))[c8];
    else         v = ((const bf16x8*)(me + (size_t)moves[b] * MEDIM))[c8 - 64];
    ((bf16x8*)(xcat + (size_t)b * (DIMD + MEDIM)))[c8] = v;
}

// ---- out[b] = dot(x5[b,:512], out_w) + out_b, one wave per row ----
__global__ __launch_bounds__(256)
void out_head(const __bf16* __restrict__ x, const float* __restrict__ out_w,
              const float* __restrict__ out_b, float* __restrict__ out)
{
    const int wid  = threadIdx.x >> 6;
    const int lane = threadIdx.x & 63;
    const int row  = blockIdx.x * 4 + wid;
    const bf16x8 xv = *(const bf16x8*)(x + (size_t)row * DIMD + lane * 8);
    const float4 w0 = ((const float4*)out_w)[lane * 2];
    const float4 w1 = ((const float4*)out_w)[lane * 2 + 1];
    float s = (float)xv[0] * w0.x + (float)xv[1] * w0.y + (float)xv[2] * w0.z +
              (float)xv[3] * w0.w + (float)xv[4] * w1.x + (float)xv[5] * w1.y +
              (float)xv[6] * w1.z + (float)xv[7] * w1.w;
#pragma unroll
    for (int off = 32; off; off >>= 1) s += __shfl_down(s, off, 64);
    if (lane == 0) out[row] = s + out_b[0];
}

extern "C" void kernel_launch(void* const* d_in, const int* in_sizes, int n_in,
                              void* d_out, int out_size, void* d_ws, size_t ws_size,
                              hipStream_t stream)
{
    const float* boards  = (const float*)d_in[0];
    const int*   flags   = (const int*)  d_in[1];
    const int*   moves   = (const int*)  d_in[3];
    const float* start   = (const float*)d_in[4];
    const float* red_w   = (const float*)d_in[5];
    const float* red_b   = (const float*)d_in[6];
    const float* ca_w    = (const float*)d_in[7];
    const float* ca_b    = (const float*)d_in[8];
    const float* cb_w    = (const float*)d_in[9];
    const float* cb_b    = (const float*)d_in[10];
    const float* move_emb= (const float*)d_in[11];
    const float* fc1_w   = (const float*)d_in[12];
    const float* fc1_b   = (const float*)d_in[13];
    const float* fc2_w   = (const float*)d_in[14];
    const float* fc2_b   = (const float*)d_in[15];
    const float* fc3_w   = (const float*)d_in[16];
    const float* fc3_b   = (const float*)d_in[17];
    const float* fc4_w   = (const float*)d_in[18];
    const float* fc4_b   = (const float*)d_in[19];
    const float* fc5_w   = (const float*)d_in[20];
    const float* fc5_b   = (const float*)d_in[21];
    const float* out_w   = (const float*)d_in[22];
    const float* out_b   = (const float*)d_in[23];

    __bf16* wsb = (__bf16*)d_ws;
    // element offsets (all multiples of 8 -> 16B aligned)
    __bf16* wpool = wsb;                         // 3,575,808
    __bf16* bstep = wsb + 3575808;               // 8192*768
    __bf16* e     = wsb + 9867264;               // 8192*512
    __bf16* eb    = wsb + 14061568;              // 8192*512
    __bf16* hA    = wsb + 18255872;              // 8192*512
    __bf16* hB    = wsb + 22450176;              // 8192*512
    __bf16* xcat  = wsb + 26644480;              // 8192*576
    __bf16* x1    = wsb + 31363072;              // 8192*512
    __bf16* x2    = wsb + 35557376;              // 8192*512
    __bf16* x3    = wsb + 39751680;              // 8192*1024
    __bf16* x4    = wsb + 48140288;              // 8192*1024
    __bf16* x5    = wsb + 56528896;              // 8192*512

    const dim3 blk(256);

    cvt_weights<<<1746, blk, 0, stream>>>(red_w, ca_w, cb_w, fc1_w, fc2_w,
                                          fc3_w, fc4_w, fc5_w, move_emb, wpool);
    bcast_h0<<<2048, blk, 0, stream>>>(start, hA);

    const dim3 g512 (DIMD / BN, BATCH / BM);     // (4,128)
    const dim3 g1024(1024 / BN, BATCH / BM);     // (8,128)

    __bf16* hcur = hA;
    __bf16* hnxt = hB;
    for (int s = 0; s < NSTEP; ++s) {
        const int* fstep = (s < 2) ? nullptr : (flags + (size_t)(s - 2) * BATCH);
        cvt_boards_step<<<3072, blk, 0, stream>>>(
            boards + (size_t)s * BATCH * EMBED, fstep, bstep);
        // e = relu(bstep @ red_w^T + red_b)
        gemm_bf16<1, false><<<g512, blk, 0, stream>>>(
            bstep, wpool + W_RED, red_b, nullptr, e, BATCH, DIMD, EMBED);
        // eb = e @ cb_w^T + cb_b
        gemm_bf16<0, false><<<g512, blk, 0, stream>>>(
            e, wpool + W_CB, cb_b, nullptr, eb, BATCH, DIMD, DIMD);
        // h = tanh(h @ ca_w^T + ca_b + eb)
        gemm_bf16<2, true><<<g512, blk, 0, stream>>>(
            hcur, wpool + W_CA, ca_b, eb, hnxt, BATCH, DIMD, DIMD);
        __bf16* t = hcur; hcur = hnxt; hnxt = t;
    }

    build_xcat<<<2304, blk, 0, stream>>>(hcur, wpool + W_ME, moves, xcat);

    gemm_bf16<1, false><<<g512, blk, 0, stream>>>(
        xcat, wpool + W_FC1, fc1_b, nullptr, x1, BATCH, DIMD, DIMD + MEDIM);
    gemm_bf16<1, false><<<g512, blk, 0, stream>>>(
        x1, wpool + W_FC2, fc2_b, nullptr, x2, BATCH, DIMD, DIMD);
    gemm_bf16<1, false><<<g1024, blk, 0, stream>>>(
        x2, wpool + W_FC3, fc3_b, nullptr, x3, BATCH, 1024, DIMD);
    gemm_bf16<1, false><<<g1024, blk, 0, stream>>>(
        x3, wpool + W_FC4, fc4_b, nullptr, x4, BATCH, 1024, 1024);
    gemm_bf16<1, false><<<g512, blk, 0, stream>>>(
        x4, wpool + W_FC5, fc5_b, nullptr, x5, BATCH, DIMD, 1024);

    out_head<<<BATCH / 4, blk, 0, stream>>>(x5, out_w, out_b, (float*)d_out);
}